// Round 13
// baseline (114.010 us; speedup 1.0000x reference)
//
#include <hip/hip_runtime.h>
#include <hip/hip_bf16.h>

typedef unsigned short u16;
using bf16x8 = __attribute__((ext_vector_type(8))) short;
using f32x4  = __attribute__((ext_vector_type(4))) float;
using f32x16 = __attribute__((ext_vector_type(16))) float;
using u32x4  = __attribute__((ext_vector_type(4))) unsigned int;

constexpr int B_ = 2, N_ = 2048, DIM_ = 1024, H_ = 16, DH_ = 64;
constexpr int M_ = B_ * N_;          // 4096 rows
constexpr int NCQ = 3 * H_ * DH_;    // 3072 qkv cols

__device__ inline u16 f2bf(float f) {
  union { float f; unsigned u; } v{f};
  unsigned r = v.u + 0x7FFF + ((v.u >> 16) & 1);
  return (u16)(r >> 16);
}

// paired bf16 store via v_cvt_pk_bf16_f32 (RNE, same as f2bf)
__device__ __forceinline__ void st_pair(u16* p0, u16* p1, float a, float b) {
  unsigned w;
  asm("v_cvt_pk_bf16_f32 %0, %1, %2" : "=v"(w) : "v"(a), "v"(b));
  *p0 = (u16)w;
  *p1 = (u16)(w >> 16);
}

__device__ __forceinline__ void gload16(const u16* g, u16* l) {
  __builtin_amdgcn_global_load_lds(
      (const __attribute__((address_space(1))) unsigned int*)g,
      (__attribute__((address_space(3))) unsigned int*)l, 16, 0, 0);
}

// ---------- prep: rmsnorm (blk<4096) | transpose w_qkv | transpose w_out ----------
__global__ void __launch_bounds__(256) prep_kernel(const float* __restrict__ x,
                                                   const float* __restrict__ gamma,
                                                   const float* __restrict__ wq,
                                                   const float* __restrict__ wo,
                                                   u16* __restrict__ normed,
                                                   u16* __restrict__ wtq,
                                                   u16* __restrict__ wto) {
  __shared__ float tile[32][33];
  int blk = blockIdx.x;
  int t = threadIdx.x;
  if (blk < M_) {
    const float4 v = reinterpret_cast<const float4*>(x + (size_t)blk * DIM_)[t];
    float ss = v.x * v.x + v.y * v.y + v.z * v.z + v.w * v.w;
#pragma unroll
    for (int o = 32; o; o >>= 1) ss += __shfl_down(ss, o, 64);
    int wid = t >> 6, lane = t & 63;
    if (lane == 0) tile[0][wid] = ss;
    __syncthreads();
    float tot = tile[0][0] + tile[0][1] + tile[0][2] + tile[0][3];
    float norm = fmaxf(sqrtf(tot), 1e-12f);
    float scale = 32.0f / norm;  // sqrt(1024)=32
    const float4 g = reinterpret_cast<const float4*>(gamma)[t];
    ushort4 o4;
    o4.x = f2bf(v.x * scale * g.x);
    o4.y = f2bf(v.y * scale * g.y);
    o4.z = f2bf(v.z * scale * g.z);
    o4.w = f2bf(v.w * scale * g.w);
    reinterpret_cast<ushort4*>(normed + (size_t)blk * DIM_)[t] = o4;
  } else {
    const float* W;
    u16* WT;
    int Nc, bc, bk;
    if (blk < M_ + 3072) {
      int idx = blk - M_;
      W = wq; WT = wtq; Nc = NCQ;
      bc = (idx % 96) * 32;
      bk = (idx / 96) * 32;
    } else {
      int idx = blk - (M_ + 3072);
      W = wo; WT = wto; Nc = DIM_;
      bc = (idx & 31) * 32;
      bk = (idx >> 5) * 32;
    }
    int tx = t & 31, ty = t >> 5;
#pragma unroll
    for (int r = ty; r < 32; r += 8)
      tile[r][tx] = W[(size_t)(bk + r) * Nc + bc + tx];
    __syncthreads();
#pragma unroll
    for (int r = ty; r < 32; r += 8)
      WT[(size_t)(bc + r) * DIM_ + bk + tx] = f2bf(tile[tx][r]);
  }
}

// ---------- GEMM (m97 structure): C[M][Nc] = A[M][K] x BT[Nc][K]^T ----------
// 1-D grid, XCD-bijective swizzle (T1). MODE 1: C f32. MODE 2: fused QKV epilogue.
template <int MODE>
__global__ void __launch_bounds__(256) gemm2_kernel(const u16* __restrict__ A,
                                                    const u16* __restrict__ BT,
                                                    void* __restrict__ Cv,
                                                    u16* __restrict__ q_s,
                                                    u16* __restrict__ k_s,
                                                    u16* __restrict__ vt,
                                                    int M, int Nc, int K) {
  __shared__ alignas(16) u16 smem[16384];  // 32KB: A dbuf 16KB | B dbuf 16KB
  int tid = threadIdx.x;
  int lane = tid & 63, wid = tid >> 6;
  int lr = lane & 15, g = lane >> 4;
  int am0 = (wid >> 1) * 64;
  int bn0 = (wid & 1) * 64;
  int nwg = gridDim.x;
  int lwg = (blockIdx.x & 7) * (nwg >> 3) + (blockIdx.x >> 3);
  int by = lwg & 31;           // row tile (M/128 = 32)
  int bx = lwg >> 5;           // col tile
  int rbase_a = by * 128;
  int rbase_b = bx * 128;

  int lineo = tid >> 3;
  int p = tid & 7;
  f32x4 acc[4][4] = {};

#define GSTAGE(base_, src_, rb_, k0_) do {                                           \
    _Pragma("unroll")                                                                \
    for (int c = 0; c < 2; c++) {                                                    \
      int line = c * 32 + lineo;                                                     \
      int sp = p ^ (line & 7);                                                       \
      int row = 2 * line + (sp >> 2);                                                \
      int j = sp & 3;                                                                \
      gload16(src_ + (size_t)(rb_ + row) * K + (k0_) + j * 8,                        \
              (base_) + c * 2048 + wid * 512);                                       \
    }                                                                                \
  } while (0)

#define STAGE(ib_, k0_) do {                                                         \
    GSTAGE(smem + (ib_) * 4096, A, rbase_a, k0_);                                    \
    GSTAGE(smem + 8192 + (ib_) * 4096, BT, rbase_b, k0_);                            \
  } while (0)

  int steps = K >> 5;
  STAGE(0, 0);
  for (int t = 0; t < steps; ++t) {
    int ibuf = t & 1;
    if (t + 1 < steps) {
      STAGE(ibuf ^ 1, (t + 1) * 32);
      asm volatile("s_waitcnt vmcnt(4)" ::: "memory");
    } else {
      asm volatile("s_waitcnt vmcnt(0)" ::: "memory");
    }
    __builtin_amdgcn_s_barrier();
    __builtin_amdgcn_sched_barrier(0);

    const char* ab = (const char*)(smem + ibuf * 4096);
    const char* bb = (const char*)(smem + 8192 + ibuf * 4096);
    bf16x8 a[4], b[4];
#pragma unroll
    for (int mi = 0; mi < 4; mi++) {
      int row = am0 + mi * 16 + lr;
      int byte = (row >> 1) * 128 + ((((row & 1) << 2) + g) ^ ((row >> 1) & 7)) * 16;
      a[mi] = *reinterpret_cast<const bf16x8*>(ab + byte);
    }
#pragma unroll
    for (int ni = 0; ni < 4; ni++) {
      int row = bn0 + ni * 16 + lr;
      int byte = (row >> 1) * 128 + ((((row & 1) << 2) + g) ^ ((row >> 1) & 7)) * 16;
      b[ni] = *reinterpret_cast<const bf16x8*>(bb + byte);
    }
#pragma unroll
    for (int mi = 0; mi < 4; mi++)
#pragma unroll
      for (int ni = 0; ni < 4; ni++)
        acc[mi][ni] = __builtin_amdgcn_mfma_f32_16x16x32_bf16(a[mi], b[ni], acc[mi][ni], 0, 0, 0);

    __builtin_amdgcn_sched_barrier(0);
    __builtin_amdgcn_s_barrier();
  }

  int orow = g * 4;
  if (MODE == 1) {
#pragma unroll
    for (int mi = 0; mi < 4; mi++)
#pragma unroll
      for (int ni = 0; ni < 4; ni++)
#pragma unroll
        for (int r = 0; r < 4; r++) {
          int row = rbase_a + am0 + 16 * mi + orow + r;
          int col = rbase_b + bn0 + 16 * ni + lr;
          ((float*)Cv)[(size_t)row * Nc + col] = acc[mi][ni][r];
        }
  } else {
    int colbase = rbase_b + bn0;
    int region = colbase >> 10;          // 0=q, 1=k, 2=v (wave-uniform)
    int head = (colbase >> 6) & 15;
    const float QS = 0.125f * 1.4426950408889634f;  // dh^-0.5 * log2(e)
    if (region < 2) {
#pragma unroll
      for (int mi = 0; mi < 4; mi++)
#pragma unroll
        for (int ni = 0; ni < 4; ni++)
#pragma unroll
          for (int r = 0; r < 4; r += 2) {
            int row = rbase_a + am0 + 16 * mi + orow + r;
            int n = row & 2047, bb_ = row >> 11;
            float v0 = acc[mi][ni][r], v1 = acc[mi][ni][r + 1];
            size_t d0 = ((size_t)(bb_ * 16 + head) * 2048 + n) * 64 + 16 * ni + lr;
            if (region == 0)
              st_pair(q_s + d0, q_s + d0 + 64, v0 * QS, v1 * QS);
            else
              st_pair(k_s + d0, k_s + d0 + 64, v0, v1);
          }
    } else {
      u16* tlds = smem + wid * 4096;  // 8KB per wave
      int n_base = (rbase_a + am0) & 2047;
      int bq = (rbase_a + am0) >> 11;
#pragma unroll
      for (int mi = 0; mi < 4; mi++)
#pragma unroll
        for (int ni = 0; ni < 4; ni++) {
          int n_loc = mi * 16 + orow;
          int dh_loc = ni * 16 + lr;
          unsigned w0, w1;
          asm("v_cvt_pk_bf16_f32 %0, %1, %2"
              : "=v"(w0) : "v"(acc[mi][ni][0]), "v"(acc[mi][ni][1]));
          asm("v_cvt_pk_bf16_f32 %0, %1, %2"
              : "=v"(w1) : "v"(acc[mi][ni][2]), "v"(acc[mi][ni][3]));
          int byte = dh_loc * 128 + ((n_loc * 2) ^ ((dh_loc & 7) << 4));
          uint2 val; val.x = w0; val.y = w1;
          *reinterpret_cast<uint2*>((char*)tlds + byte) = val;
        }
#pragma unroll
      for (int it = 0; it < 8; it++) {
        int dh_loc = it * 8 + (lane >> 3);
        int n8 = (lane & 7) * 8;
        int byte = dh_loc * 128 + ((n8 * 2) ^ ((dh_loc & 7) << 4));
        bf16x8 v = *reinterpret_cast<const bf16x8*>((const char*)tlds + byte);
        size_t dst = ((size_t)(bq * 16 + head) * 64 + dh_loc) * 2048 + n_base + n8;
        *reinterpret_cast<bf16x8*>(vt + dst) = v;
      }
    }
  }
#undef STAGE
#undef GSTAGE
}

// ---------- flash attention v11: attn9 skeleton + V-direct (T14) ----------
// Same proven 4-wave / counted-vmcnt / barrier structure as attn9, but ONLY K is
// LDS-staged (STAGE = 2 gloads, vmcnt(6)); V fragments are per-lane L2 loads
// issued at loop-top (each wave reads only its own myhalf key-half of V), so
// they ride ~400cy of QK+softmax before PV consumes them. LDS 17KB.
__global__ void __launch_bounds__(256) attn11_kernel(const u16* __restrict__ q_s,
                                                     const u16* __restrict__ k_s,
                                                     const u16* __restrict__ vt,
                                                     u16* __restrict__ ao) {
  __shared__ alignas(16) u16 smem[8704];  // 17KB: K dbuf 16KB (combine reuses 17KB)
  u16* kb0 = smem;
  int tid = threadIdx.x;
  int lane = tid & 63, wid = tid >> 6;
  int q31 = lane & 31, hi = lane >> 5;
  int strip = wid >> 1, myhalf = wid & 1;
  int blk = blockIdx.x;
  int bh = blk & 31;
  int s = blk >> 5;                       // 0..31
  int u = s & 7, gq = s >> 3;
  int j = (gq == 0) ? (31 - u) : (gq == 1) ? (16 + u) : (gq == 2) ? (15 - u) : u;
  int b = bh >> 4, h = bh & 15;
  const u16* qp = q_s + (size_t)bh * N_ * DH_;
  const u16* kp = k_s + (size_t)bh * N_ * DH_;
  const u16* vp = vt + (size_t)bh * DH_ * N_;
  int q0w = j * 64 + strip * 32;
  int qi = q0w + q31;
  int steps = j + 1;

  bf16x8 qf[4];
#pragma unroll
  for (int c = 0; c < 4; c++)
    qf[c] = *reinterpret_cast<const bf16x8*>(qp + (size_t)(q0w + q31) * 64 + c * 16 + hi * 8);

  f32x16 o0 = {}, o1 = {};
  float lsum = 0.f;

  int srow = lane >> 3;
  int scol = (lane & 7) ^ srow;
  int c0 = wid * 2, c1 = c0 + 1;
  // per-lane V bases: rows d=q31 and d=32+q31; key base = tile kv + myhalf*32
  const u16* vb0 = vp + (size_t)q31 * N_ + myhalf * 32 + hi * 8;
  const u16* vb1 = vb0 + (size_t)32 * N_;

#define STAGE(ibuf_, kv0_) do {                                                              \
    gload16(kp + (size_t)((kv0_) + c0 * 8 + srow) * 64 + scol * 8,                           \
            kb0 + (ibuf_) * 4096 + c0 * 512);                                                \
    gload16(kp + (size_t)((kv0_) + c1 * 8 + srow) * 64 + scol * 8,                           \
            kb0 + (ibuf_) * 4096 + c1 * 512);                                                \
  } while (0)

  STAGE(0, 0);

  for (int t = 0; t < steps; ++t) {
    int ibuf = t & 1;
    // V fragments issued FIRST (consumed at PV, ~400cy later; L2-hot)
    bf16x8 vf00 = *reinterpret_cast<const bf16x8*>(vb0 + t * 64);
    bf16x8 vf01 = *reinterpret_cast<const bf16x8*>(vb0 + t * 64 + 16);
    bf16x8 vf10 = *reinterpret_cast<const bf16x8*>(vb1 + t * 64);
    bf16x8 vf11 = *reinterpret_cast<const bf16x8*>(vb1 + t * 64 + 16);
    if (t + 1 < steps) {
      STAGE(ibuf ^ 1, (t + 1) * 64);
      // outstanding: stage-t(2,oldest) + V-t(4) + stage-t+1(2) -> drain stage-t
      asm volatile("s_waitcnt vmcnt(6)" ::: "memory");
    } else {
      asm volatile("s_waitcnt vmcnt(4)" ::: "memory");
    }
    __builtin_amdgcn_s_barrier();
    __builtin_amdgcn_sched_barrier(0);

    const u16* kb = kb0 + ibuf * 4096;
    int kv = t * 64 + myhalf * 32;
    if (kv <= q0w + 31) {
      // S^T[key][q] = mfma(K-frag, Q-frag)
      f32x16 st = {};
      int krow = myhalf * 32 + q31;
      int ksw = (krow & 7) << 4;
      __builtin_amdgcn_s_setprio(1);
#pragma unroll
      for (int c = 0; c < 4; c++) {
        bf16x8 kf = *reinterpret_cast<const bf16x8*>(
            (const char*)kb + krow * 128 + (((c * 2 + hi) * 16) ^ ksw));
        st = __builtin_amdgcn_mfma_f32_32x32x16_bf16(kf, qf[c], st, 0, 0, 0);
      }
      __builtin_amdgcn_s_setprio(0);
      // p = exp2(s'); offset-free (cancels in O = sum(p v)/sum(p))
      float p[16];
      bool diag = (kv + 31 > q0w);
      if (diag) {
#pragma unroll
        for (int r = 0; r < 16; r++) {
          int key = kv + (r & 3) + 8 * (r >> 2) + 4 * hi;
          float e = __builtin_amdgcn_exp2f(st[r]);
          p[r] = (key > qi) ? 0.f : e;
        }
      } else {
#pragma unroll
        for (int r = 0; r < 16; r++) p[r] = __builtin_amdgcn_exp2f(st[r]);
      }
#pragma unroll
      for (int r = 0; r < 16; r++) lsum += p[r];
      // pack quads: cw0[j] = keys {8j+4hi, 8j+4hi+1}, cw1[j] = {8j+4hi+2, +3}
      unsigned cw0[4], cw1[4];
#pragma unroll
      for (int jq2 = 0; jq2 < 4; jq2++) {
        asm("v_cvt_pk_bf16_f32 %0, %1, %2" : "=v"(cw0[jq2]) : "v"(p[4 * jq2]), "v"(p[4 * jq2 + 1]));
        asm("v_cvt_pk_bf16_f32 %0, %1, %2" : "=v"(cw1[jq2]) : "v"(p[4 * jq2 + 2]), "v"(p[4 * jq2 + 3]));
      }
      // select-first exchange: send what partner needs, 2 shfl per kc
#pragma unroll
      for (int kc = 0; kc < 2; kc++) {
        unsigned c0a = cw0[2 * kc], c0b = cw0[2 * kc + 1];
        unsigned c1a = cw1[2 * kc], c1b = cw1[2 * kc + 1];
        unsigned sel0 = hi ? c0a : c0b;
        unsigned sel1 = hi ? c1a : c1b;
        unsigned r0 = (unsigned)__shfl_xor((int)sel0, 32, 64);
        unsigned r1 = (unsigned)__shfl_xor((int)sel1, 32, 64);
        u32x4 w;
        w[0] = hi ? r0 : c0a;
        w[1] = hi ? r1 : c1a;
        w[2] = hi ? c0b : r0;
        w[3] = hi ? c1b : r1;
        bf16x8 pa = __builtin_bit_cast(bf16x8, w);
        __builtin_amdgcn_s_setprio(1);
        o0 = __builtin_amdgcn_mfma_f32_32x32x16_bf16(pa, kc ? vf01 : vf00, o0, 0, 0, 0);
        o1 = __builtin_amdgcn_mfma_f32_32x32x16_bf16(pa, kc ? vf11 : vf10, o1, 0, 0, 0);
        __builtin_amdgcn_s_setprio(0);
      }
    }
    __builtin_amdgcn_sched_barrier(0);
    __builtin_amdgcn_s_barrier();
  }

  // combine wave pairs (w, w^1): partials are linear (offset-free softmax)
  __syncthreads();
  float lc = lsum + __shfl_xor(lsum, 32, 64);
  float* cb = (float*)smem;
  int pr = wid >> 1;
  if (myhalf) {
#pragma unroll
    for (int r = 0; r < 16; r++) {
      cb[pr * 2048 + r * 64 + lane] = o0[r];
      cb[pr * 2048 + (16 + r) * 64 + lane] = o1[r];
    }
    cb[4096 + pr * 64 + lane] = lc;
  }
  __syncthreads();
  if (!myhalf) {
#pragma unroll
    for (int r = 0; r < 16; r++) {
      o0[r] += cb[pr * 2048 + r * 64 + lane];
      o1[r] += cb[pr * 2048 + (16 + r) * 64 + lane];
    }
    float ltot = fmaxf(lc + cb[4096 + pr * 64 + lane], 1e-30f);
    float linv = 1.0f / ltot;
#pragma unroll
    for (int r = 0; r < 16; r += 2) {
      int qrow0 = (r & 3) + 8 * (r >> 2) + 4 * hi;  // even r: qrow0, qrow0+1
      float li0 = __shfl(linv, qrow0, 64);
      float li1 = __shfl(linv, qrow0 + 1, 64);
      size_t base0 = (size_t)(b * N_ + q0w + qrow0) * 1024 + h * 64;
      st_pair(ao + base0 + q31, ao + base0 + 1024 + q31, o0[r] * li0, o0[r + 1] * li1);
      st_pair(ao + base0 + 32 + q31, ao + base0 + 1024 + 32 + q31, o1[r] * li0, o1[r + 1] * li1);
    }
  }
#undef STAGE
}

extern "C" void kernel_launch(void* const* d_in, const int* in_sizes, int n_in,
                              void* d_out, int out_size, void* d_ws, size_t ws_size,
                              hipStream_t stream) {
  const float* x = (const float*)d_in[0];
  const float* gamma = (const float*)d_in[1];
  const float* w_qkv = (const float*)d_in[2];
  const float* w_out = (const float*)d_in[3];
  float* out = (float*)d_out;

  char* p = (char*)d_ws;
  u16* normed = (u16*)p; p += (size_t)M_ * DIM_ * 2;   // 8MB (gemm A input)
  u16* wt_qkv = (u16*)p; p += (size_t)NCQ * DIM_ * 2;  // 6MB
  u16* wt_out = (u16*)p; p += (size_t)DIM_ * DIM_ * 2; // 2MB
  u16* k_s = (u16*)p;    p += (size_t)M_ * DIM_ * 2;   // 8MB
  u16* vt = (u16*)p;     p += (size_t)M_ * DIM_ * 2;   // 8MB
  u16* q_s = (u16*)p;    p += (size_t)M_ * DIM_ * 2;   // 8MB
  u16* ao = (u16*)p;     p += (size_t)M_ * DIM_ * 2;   // 8MB

  hipLaunchKernelGGL(prep_kernel, dim3(M_ + 3072 + 1024), dim3(256), 0, stream,
                     x, gamma, w_qkv, w_out, normed, wt_qkv, wt_out);
  hipLaunchKernelGGL(gemm2_kernel<2>, dim3((NCQ / 128) * (M_ / 128)), dim3(256), 0, stream,
                     normed, wt_qkv, nullptr, q_s, k_s, vt, M_, NCQ, DIM_);
  hipLaunchKernelGGL(attn11_kernel, dim3(B_ * H_ * (N_ / 64)), dim3(256), 0, stream,
                     q_s, k_s, vt, ao);
  hipLaunchKernelGGL(gemm2_kernel<1>, dim3((DIM_ / 128) * (M_ / 128)), dim3(256), 0, stream,
                     ao, wt_out, (void*)out, nullptr, nullptr, nullptr, M_, DIM_, DIM_);
}

// Round 14
// 100.102 us; speedup vs baseline: 1.1389x; 1.1389x over previous
//
#include <hip/hip_runtime.h>
#include <hip/hip_bf16.h>

typedef unsigned short u16;
using bf16x8 = __attribute__((ext_vector_type(8))) short;
using f32x4  = __attribute__((ext_vector_type(4))) float;
using f32x16 = __attribute__((ext_vector_type(16))) float;
using u32x4  = __attribute__((ext_vector_type(4))) unsigned int;

constexpr int B_ = 2, N_ = 2048, DIM_ = 1024, H_ = 16, DH_ = 64;
constexpr int M_ = B_ * N_;          // 4096 rows
constexpr int NCQ = 3 * H_ * DH_;    // 3072 qkv cols

__device__ inline u16 f2bf(float f) {
  union { float f; unsigned u; } v{f};
  unsigned r = v.u + 0x7FFF + ((v.u >> 16) & 1);
  return (u16)(r >> 16);
}

// paired bf16 store via v_cvt_pk_bf16_f32 (RNE, same as f2bf)
__device__ __forceinline__ void st_pair(u16* p0, u16* p1, float a, float b) {
  unsigned w;
  asm("v_cvt_pk_bf16_f32 %0, %1, %2" : "=v"(w) : "v"(a), "v"(b));
  *p0 = (u16)w;
  *p1 = (u16)(w >> 16);
}

__device__ __forceinline__ void gload16(const u16* g, u16* l) {
  __builtin_amdgcn_global_load_lds(
      (const __attribute__((address_space(1))) unsigned int*)g,
      (__attribute__((address_space(3))) unsigned int*)l, 16, 0, 0);
}

// ---------- prep: rmsnorm (blk<4096) | transpose w_qkv | transpose w_out ----------
// Fused to remove 2 launch gaps; the three ops are independent.
__global__ void __launch_bounds__(256) prep_kernel(const float* __restrict__ x,
                                                   const float* __restrict__ gamma,
                                                   const float* __restrict__ wq,
                                                   const float* __restrict__ wo,
                                                   u16* __restrict__ normed,
                                                   u16* __restrict__ wtq,
                                                   u16* __restrict__ wto) {
  __shared__ float tile[32][33];
  int blk = blockIdx.x;
  int t = threadIdx.x;
  if (blk < M_) {
    // RMSNorm row = blk
    const float4 v = reinterpret_cast<const float4*>(x + (size_t)blk * DIM_)[t];
    float ss = v.x * v.x + v.y * v.y + v.z * v.z + v.w * v.w;
#pragma unroll
    for (int o = 32; o; o >>= 1) ss += __shfl_down(ss, o, 64);
    int wid = t >> 6, lane = t & 63;
    if (lane == 0) tile[0][wid] = ss;
    __syncthreads();
    float tot = tile[0][0] + tile[0][1] + tile[0][2] + tile[0][3];
    float norm = fmaxf(sqrtf(tot), 1e-12f);
    float scale = 32.0f / norm;  // sqrt(1024)=32
    const float4 g = reinterpret_cast<const float4*>(gamma)[t];
    ushort4 o4;
    o4.x = f2bf(v.x * scale * g.x);
    o4.y = f2bf(v.y * scale * g.y);
    o4.z = f2bf(v.z * scale * g.z);
    o4.w = f2bf(v.w * scale * g.w);
    reinterpret_cast<ushort4*>(normed + (size_t)blk * DIM_)[t] = o4;
  } else {
    // weight transpose: W[K=1024][Nc] fp32 -> WT[Nc][1024] bf16
    const float* W;
    u16* WT;
    int Nc, bc, bk;
    if (blk < M_ + 3072) {
      int idx = blk - M_;            // 3072 tiles: x=idx%96 (col), y=idx/96 (row)
      W = wq; WT = wtq; Nc = NCQ;
      bc = (idx % 96) * 32;
      bk = (idx / 96) * 32;
    } else {
      int idx = blk - (M_ + 3072);   // 1024 tiles: 32x32
      W = wo; WT = wto; Nc = DIM_;
      bc = (idx & 31) * 32;
      bk = (idx >> 5) * 32;
    }
    int tx = t & 31, ty = t >> 5;
#pragma unroll
    for (int r = ty; r < 32; r += 8)
      tile[r][tx] = W[(size_t)(bk + r) * Nc + bc + tx];
    __syncthreads();
#pragma unroll
    for (int r = ty; r < 32; r += 8)
      WT[(size_t)(bc + r) * DIM_ + bk + tx] = f2bf(tile[tx][r]);
  }
}

// ---------- GEMM (m97 structure): C[M][Nc] = A[M][K] x BT[Nc][K]^T ----------
// 1-D grid, XCD-bijective swizzle (T1): XCD k owns a contiguous column-major
// chunk of tiles -> its B-panels stay L2-hot across all 32 row-tiles.
// MODE 1: C = f32 [M][Nc].
// MODE 2: fused QKV epilogue -> q_s (xQS), k_s, and vt (V transposed in-epilogue).
template <int MODE>
__global__ void __launch_bounds__(256) gemm2_kernel(const u16* __restrict__ A,
                                                    const u16* __restrict__ BT,
                                                    void* __restrict__ Cv,
                                                    u16* __restrict__ q_s,
                                                    u16* __restrict__ k_s,
                                                    u16* __restrict__ vt,
                                                    int M, int Nc, int K) {
  __shared__ alignas(16) u16 smem[16384];  // 32KB: A dbuf 16KB | B dbuf 16KB
  int tid = threadIdx.x;
  int lane = tid & 63, wid = tid >> 6;
  int lr = lane & 15, g = lane >> 4;
  int am0 = (wid >> 1) * 64;
  int bn0 = (wid & 1) * 64;
  int nwg = gridDim.x;
  int lwg = (blockIdx.x & 7) * (nwg >> 3) + (blockIdx.x >> 3);
  int by = lwg & 31;           // row tile (M/128 = 32)
  int bx = lwg >> 5;           // col tile
  int rbase_a = by * 128;
  int rbase_b = bx * 128;

  int lineo = tid >> 3;
  int p = tid & 7;
  f32x4 acc[4][4] = {};

#define GSTAGE(base_, src_, rb_, k0_) do {                                           \
    _Pragma("unroll")                                                                \
    for (int c = 0; c < 2; c++) {                                                    \
      int line = c * 32 + lineo;                                                     \
      int sp = p ^ (line & 7);                                                       \
      int row = 2 * line + (sp >> 2);                                                \
      int j = sp & 3;                                                                \
      gload16(src_ + (size_t)(rb_ + row) * K + (k0_) + j * 8,                        \
              (base_) + c * 2048 + wid * 512);                                       \
    }                                                                                \
  } while (0)

#define STAGE(ib_, k0_) do {                                                         \
    GSTAGE(smem + (ib_) * 4096, A, rbase_a, k0_);                                    \
    GSTAGE(smem + 8192 + (ib_) * 4096, BT, rbase_b, k0_);                            \
  } while (0)

  int steps = K >> 5;
  STAGE(0, 0);
  for (int t = 0; t < steps; ++t) {
    int ibuf = t & 1;
    if (t + 1 < steps) {
      STAGE(ibuf ^ 1, (t + 1) * 32);
      asm volatile("s_waitcnt vmcnt(4)" ::: "memory");
    } else {
      asm volatile("s_waitcnt vmcnt(0)" ::: "memory");
    }
    __builtin_amdgcn_s_barrier();
    __builtin_amdgcn_sched_barrier(0);

    const char* ab = (const char*)(smem + ibuf * 4096);
    const char* bb = (const char*)(smem + 8192 + ibuf * 4096);
    bf16x8 a[4], b[4];
#pragma unroll
    for (int mi = 0; mi < 4; mi++) {
      int row = am0 + mi * 16 + lr;
      int byte = (row >> 1) * 128 + ((((row & 1) << 2) + g) ^ ((row >> 1) & 7)) * 16;
      a[mi] = *reinterpret_cast<const bf16x8*>(ab + byte);
    }
#pragma unroll
    for (int ni = 0; ni < 4; ni++) {
      int row = bn0 + ni * 16 + lr;
      int byte = (row >> 1) * 128 + ((((row & 1) << 2) + g) ^ ((row >> 1) & 7)) * 16;
      b[ni] = *reinterpret_cast<const bf16x8*>(bb + byte);
    }
#pragma unroll
    for (int mi = 0; mi < 4; mi++)
#pragma unroll
      for (int ni = 0; ni < 4; ni++)
        acc[mi][ni] = __builtin_amdgcn_mfma_f32_16x16x32_bf16(a[mi], b[ni], acc[mi][ni], 0, 0, 0);

    __builtin_amdgcn_sched_barrier(0);
    __builtin_amdgcn_s_barrier();
  }

  int orow = g * 4;
  if (MODE == 1) {
#pragma unroll
    for (int mi = 0; mi < 4; mi++)
#pragma unroll
      for (int ni = 0; ni < 4; ni++)
#pragma unroll
        for (int r = 0; r < 4; r++) {
          int row = rbase_a + am0 + 16 * mi + orow + r;
          int col = rbase_b + bn0 + 16 * ni + lr;
          ((float*)Cv)[(size_t)row * Nc + col] = acc[mi][ni][r];
        }
  } else {
    // fused QKV epilogue; each wave's 64-col range lies in exactly one region
    int colbase = rbase_b + bn0;
    int region = colbase >> 10;          // 0=q, 1=k, 2=v (wave-uniform)
    int head = (colbase >> 6) & 15;
    const float QS = 0.125f * 1.4426950408889634f;  // dh^-0.5 * log2(e)
    if (region < 2) {
#pragma unroll
      for (int mi = 0; mi < 4; mi++)
#pragma unroll
        for (int ni = 0; ni < 4; ni++)
#pragma unroll
          for (int r = 0; r < 4; r += 2) {
            int row = rbase_a + am0 + 16 * mi + orow + r;  // even; row+1 same b
            int n = row & 2047, bb_ = row >> 11;
            float v0 = acc[mi][ni][r], v1 = acc[mi][ni][r + 1];
            size_t d0 = ((size_t)(bb_ * 16 + head) * 2048 + n) * 64 + 16 * ni + lr;
            if (region == 0)
              st_pair(q_s + d0, q_s + d0 + 64, v0 * QS, v1 * QS);
            else
              st_pair(k_s + d0, k_s + d0 + 64, v0, v1);
          }
    } else {
      // V: wave-local LDS transpose (staging LDS is free after the final barrier).
      u16* tlds = smem + wid * 4096;  // 8KB per wave
      int n_base = (rbase_a + am0) & 2047;
      int bq = (rbase_a + am0) >> 11;
#pragma unroll
      for (int mi = 0; mi < 4; mi++)
#pragma unroll
        for (int ni = 0; ni < 4; ni++) {
          int n_loc = mi * 16 + orow;
          int dh_loc = ni * 16 + lr;
          unsigned w0, w1;
          asm("v_cvt_pk_bf16_f32 %0, %1, %2"
              : "=v"(w0) : "v"(acc[mi][ni][0]), "v"(acc[mi][ni][1]));
          asm("v_cvt_pk_bf16_f32 %0, %1, %2"
              : "=v"(w1) : "v"(acc[mi][ni][2]), "v"(acc[mi][ni][3]));
          int byte = dh_loc * 128 + ((n_loc * 2) ^ ((dh_loc & 7) << 4));
          uint2 val; val.x = w0; val.y = w1;
          *reinterpret_cast<uint2*>((char*)tlds + byte) = val;
        }
#pragma unroll
      for (int it = 0; it < 8; it++) {
        int dh_loc = it * 8 + (lane >> 3);
        int n8 = (lane & 7) * 8;
        int byte = dh_loc * 128 + ((n8 * 2) ^ ((dh_loc & 7) << 4));
        bf16x8 v = *reinterpret_cast<const bf16x8*>((const char*)tlds + byte);
        size_t dst = ((size_t)(bq * 16 + head) * 64 + dh_loc) * 2048 + n_base + n8;
        *reinterpret_cast<bf16x8*>(vt + dst) = v;
      }
    }
  }
#undef STAGE
#undef GSTAGE
}

// ---------- flash attention v9 (proven 100.7-total config): attn5 + balanced snake ----------
// 64 q-rows/block, 4 waves = 2 strips x 2 KV-half-parity; K/V LDS dbuf 32KB,
// global_load_lds w16, counted vmcnt(4); offset-free exp2 softmax (linear
// partials); select-first cross-half exchange; setprio on MFMA clusters.
// j-map: 4-group snake so each round-robin CU slot group sums to 62 steps.
__global__ void __launch_bounds__(256) attn9_kernel(const u16* __restrict__ q_s,
                                                    const u16* __restrict__ k_s,
                                                    const u16* __restrict__ vt,
                                                    u16* __restrict__ ao) {
  __shared__ alignas(16) u16 smem[16384];  // 32KB: K dbuf 16KB | V dbuf 16KB
  u16* kb0 = smem;
  u16* vb0 = smem + 8192;
  int tid = threadIdx.x;
  int lane = tid & 63, wid = tid >> 6;
  int q31 = lane & 31, hi = lane >> 5;
  int strip = wid >> 1, myhalf = wid & 1;
  int blk = blockIdx.x;
  int bh = blk & 31;
  int s = blk >> 5;                       // 0..31
  int u = s & 7, gq = s >> 3;
  int j = (gq == 0) ? (31 - u) : (gq == 1) ? (16 + u) : (gq == 2) ? (15 - u) : u;
  int b = bh >> 4, h = bh & 15;
  const u16* qp = q_s + (size_t)bh * N_ * DH_;
  const u16* kp = k_s + (size_t)bh * N_ * DH_;
  const u16* vp = vt + (size_t)bh * DH_ * N_;
  int q0w = j * 64 + strip * 32;
  int qi = q0w + q31;
  int steps = j + 1;

  bf16x8 qf[4];
#pragma unroll
  for (int c = 0; c < 4; c++)
    qf[c] = *reinterpret_cast<const bf16x8*>(qp + (size_t)(q0w + q31) * 64 + c * 16 + hi * 8);

  f32x16 o0 = {}, o1 = {};
  float lsum = 0.f;

  int srow = lane >> 3;
  int scol = (lane & 7) ^ srow;
  int c0 = wid * 2, c1 = c0 + 1;

#define STAGE(ibuf_, kv0_) do {                                                              \
    gload16(kp + (size_t)((kv0_) + c0 * 8 + srow) * 64 + scol * 8,                           \
            kb0 + (ibuf_) * 4096 + c0 * 512);                                                \
    gload16(kp + (size_t)((kv0_) + c1 * 8 + srow) * 64 + scol * 8,                           \
            kb0 + (ibuf_) * 4096 + c1 * 512);                                                \
    gload16(vp + (size_t)(c0 * 8 + srow) * N_ + (kv0_) + scol * 8,                           \
            vb0 + (ibuf_) * 4096 + c0 * 512);                                                \
    gload16(vp + (size_t)(c1 * 8 + srow) * N_ + (kv0_) + scol * 8,                           \
            vb0 + (ibuf_) * 4096 + c1 * 512);                                                \
  } while (0)

  STAGE(0, 0);

  for (int t = 0; t < steps; ++t) {
    int ibuf = t & 1;
    if (t + 1 < steps) {
      STAGE(ibuf ^ 1, (t + 1) * 64);
      asm volatile("s_waitcnt vmcnt(4)" ::: "memory");
    } else {
      asm volatile("s_waitcnt vmcnt(0)" ::: "memory");
    }
    __builtin_amdgcn_s_barrier();
    __builtin_amdgcn_sched_barrier(0);

    const u16* kb = kb0 + ibuf * 4096;
    const u16* vb = vb0 + ibuf * 4096;
    int kv = t * 64 + myhalf * 32;
    if (kv <= q0w + 31) {
      // S^T[key][q] = mfma(K-frag, Q-frag)
      f32x16 st = {};
      int krow = myhalf * 32 + q31;
      int ksw = (krow & 7) << 4;
      __builtin_amdgcn_s_setprio(1);
#pragma unroll
      for (int c = 0; c < 4; c++) {
        bf16x8 kf = *reinterpret_cast<const bf16x8*>(
            (const char*)kb + krow * 128 + (((c * 2 + hi) * 16) ^ ksw));
        st = __builtin_amdgcn_mfma_f32_32x32x16_bf16(kf, qf[c], st, 0, 0, 0);
      }
      __builtin_amdgcn_s_setprio(0);
      // p = exp2(s'); offset-free (cancels in O = sum(p v)/sum(p))
      float p[16];
      bool diag = (kv + 31 > q0w);
      if (diag) {
#pragma unroll
        for (int r = 0; r < 16; r++) {
          int key = kv + (r & 3) + 8 * (r >> 2) + 4 * hi;
          float e = __builtin_amdgcn_exp2f(st[r]);
          p[r] = (key > qi) ? 0.f : e;
        }
      } else {
#pragma unroll
        for (int r = 0; r < 16; r++) p[r] = __builtin_amdgcn_exp2f(st[r]);
      }
#pragma unroll
      for (int r = 0; r < 16; r++) lsum += p[r];
      // pack quads: cw0[j] = keys {8j+4hi, 8j+4hi+1}, cw1[j] = {8j+4hi+2, +3}
      unsigned cw0[4], cw1[4];
#pragma unroll
      for (int jq2 = 0; jq2 < 4; jq2++) {
        asm("v_cvt_pk_bf16_f32 %0, %1, %2" : "=v"(cw0[jq2]) : "v"(p[4 * jq2]), "v"(p[4 * jq2 + 1]));
        asm("v_cvt_pk_bf16_f32 %0, %1, %2" : "=v"(cw1[jq2]) : "v"(p[4 * jq2 + 2]), "v"(p[4 * jq2 + 3]));
      }
      // select-first exchange: send what partner needs, 2 shfl per kc
#pragma unroll
      for (int kc = 0; kc < 2; kc++) {
        unsigned c0a = cw0[2 * kc], c0b = cw0[2 * kc + 1];
        unsigned c1a = cw1[2 * kc], c1b = cw1[2 * kc + 1];
        unsigned sel0 = hi ? c0a : c0b;
        unsigned sel1 = hi ? c1a : c1b;
        unsigned r0 = (unsigned)__shfl_xor((int)sel0, 32, 64);
        unsigned r1 = (unsigned)__shfl_xor((int)sel1, 32, 64);
        u32x4 w;
        w[0] = hi ? r0 : c0a;
        w[1] = hi ? r1 : c1a;
        w[2] = hi ? c0b : r0;
        w[3] = hi ? c1b : r1;
        bf16x8 pa = __builtin_bit_cast(bf16x8, w);
        int slot = (myhalf * 4 + kc * 2 + hi) * 16;
        int vsw = (q31 & 7) << 4;
        bf16x8 vf0 = *reinterpret_cast<const bf16x8*>(
            (const char*)vb + q31 * 128 + (slot ^ vsw));
        bf16x8 vf1 = *reinterpret_cast<const bf16x8*>(
            (const char*)vb + (32 + q31) * 128 + (slot ^ vsw));
        __builtin_amdgcn_s_setprio(1);
        o0 = __builtin_amdgcn_mfma_f32_32x32x16_bf16(pa, vf0, o0, 0, 0, 0);
        o1 = __builtin_amdgcn_mfma_f32_32x32x16_bf16(pa, vf1, o1, 0, 0, 0);
        __builtin_amdgcn_s_setprio(0);
      }
    }
    __builtin_amdgcn_sched_barrier(0);
    __builtin_amdgcn_s_barrier();
  }

  // combine wave pairs (w, w^1): partials are linear (offset-free softmax)
  __syncthreads();
  float lc = lsum + __shfl_xor(lsum, 32, 64);
  float* cb = (float*)smem;
  int pr = wid >> 1;
  if (myhalf) {
#pragma unroll
    for (int r = 0; r < 16; r++) {
      cb[pr * 2048 + r * 64 + lane] = o0[r];
      cb[pr * 2048 + (16 + r) * 64 + lane] = o1[r];
    }
    cb[4096 + pr * 64 + lane] = lc;
  }
  __syncthreads();
  if (!myhalf) {
#pragma unroll
    for (int r = 0; r < 16; r++) {
      o0[r] += cb[pr * 2048 + r * 64 + lane];
      o1[r] += cb[pr * 2048 + (16 + r) * 64 + lane];
    }
    float ltot = fmaxf(lc + cb[4096 + pr * 64 + lane], 1e-30f);
    float linv = 1.0f / ltot;
#pragma unroll
    for (int r = 0; r < 16; r += 2) {
      int qrow0 = (r & 3) + 8 * (r >> 2) + 4 * hi;  // even r: qrow0, qrow0+1
      float li0 = __shfl(linv, qrow0, 64);
      float li1 = __shfl(linv, qrow0 + 1, 64);
      size_t base0 = (size_t)(b * N_ + q0w + qrow0) * 1024 + h * 64;
      st_pair(ao + base0 + q31, ao + base0 + 1024 + q31, o0[r] * li0, o0[r + 1] * li1);
      st_pair(ao + base0 + 32 + q31, ao + base0 + 1024 + 32 + q31, o1[r] * li0, o1[r + 1] * li1);
    }
  }
#undef STAGE
}

extern "C" void kernel_launch(void* const* d_in, const int* in_sizes, int n_in,
                              void* d_out, int out_size, void* d_ws, size_t ws_size,
                              hipStream_t stream) {
  const float* x = (const float*)d_in[0];
  const float* gamma = (const float*)d_in[1];
  const float* w_qkv = (const float*)d_in[2];
  const float* w_out = (const float*)d_in[3];
  float* out = (float*)d_out;

  char* p = (char*)d_ws;
  u16* normed = (u16*)p; p += (size_t)M_ * DIM_ * 2;   // 8MB (gemm A input)
  u16* wt_qkv = (u16*)p; p += (size_t)NCQ * DIM_ * 2;  // 6MB
  u16* wt_out = (u16*)p; p += (size_t)DIM_ * DIM_ * 2; // 2MB
  u16* k_s = (u16*)p;    p += (size_t)M_ * DIM_ * 2;   // 8MB
  u16* vt = (u16*)p;     p += (size_t)M_ * DIM_ * 2;   // 8MB
  u16* q_s = (u16*)p;    p += (size_t)M_ * DIM_ * 2;   // 8MB
  u16* ao = (u16*)p;     p += (size_t)M_ * DIM_ * 2;   // 8MB

  hipLaunchKernelGGL(prep_kernel, dim3(M_ + 3072 + 1024), dim3(256), 0, stream,
                     x, gamma, w_qkv, w_out, normed, wt_qkv, wt_out);
  hipLaunchKernelGGL(gemm2_kernel<2>, dim3((NCQ / 128) * (M_ / 128)), dim3(256), 0, stream,
                     normed, wt_qkv, nullptr, q_s, k_s, vt, M_, NCQ, DIM_);
  hipLaunchKernelGGL(attn9_kernel, dim3(B_ * H_ * (N_ / 64)), dim3(256), 0, stream,
                     q_s, k_s, vt, ao);
  hipLaunchKernelGGL(gemm2_kernel<1>, dim3((DIM_ / 128) * (M_ / 128)), dim3(256), 0, stream,
                     ao, wt_out, (void*)out, nullptr, nullptr, nullptr, M_, DIM_, DIM_);
}